// Round 8
// baseline (198.955 us; speedup 1.0000x reference)
//
#include <hip/hip_runtime.h>

// RoiCut: out[i, c, y, x] = fm[assoc[i], c, y0_i + y, x0_i + x]
// fm: [8, 256, 200, 200] fp32, boxes_yx: [512, 2] int32 (y0, x0), assoc: [512] int32
// out: [512, 256, 32, 32] fp32
//
// R7 strategy: no LDS, no barriers — let the XCD L2 be the staging buffer.
//  - block = (sample, channel); its ~64 boxes are processed in y0-sorted order
//    (8-row-bucket counting sort), so the block's read band is ~30 rows ~ 25 KB
//    of its 160 KB plane. 64 resident plane-blocks/XCD -> ~1.8 MB band << 4 MB L2:
//    first touch fetches a line from HBM once, box-overlap reuse hits L2.
//  - kills R4's 8-way LDS read conflict (~58 us/CU), the barrier phase-lock,
//    and the fetch of never-boxed lines (~15% of the plane).
//  - no barriers -> waves drift -> read+write streams mix at HBM naturally.
//  - non-temporal stores keep the 512 MB write stream from evicting read bands.

typedef float v4f __attribute__((ext_vector_type(4)));

constexpr int C_    = 256;
constexpr int H_    = 200;
constexpr int W_    = 200;
constexpr int BOX_  = 32;
constexpr int N_    = 512;
constexpr int B_    = 8;
constexpr int PLANE = H_ * W_;          // 40000 floats
constexpr int YB    = 8;                // y-bucket granularity for the sort
constexpr int NYB   = (H_ + YB - 1) / YB;   // 25 buckets
constexpr int NBIN  = B_ * NYB;         // 200 (sample, y-bucket) bins
constexpr int NBINP = 256;              // padded to pow2 for the scan

__global__ __launch_bounds__(512) void group_boxes_kernel(
    const int* __restrict__ boxes,
    const int* __restrict__ assoc,
    unsigned int* __restrict__ keys,
    int* __restrict__ starts)
{
    __shared__ int cnt[NBINP];
    __shared__ int scan[NBINP];
    __shared__ int baseS[NBINP];
    int t = threadIdx.x;   // 512 threads, one per box

    if (t < NBINP) cnt[t] = 0;
    __syncthreads();

    int y0 = boxes[2 * t];
    int x0 = boxes[2 * t + 1];
    y0 = min(max(y0, 0), H_ - BOX_);
    x0 = min(max(x0, 0), W_ - BOX_);
    int a = assoc[t];
    int bin = a * NYB + y0 / YB;
    // key: [y0:8 | x0:8 | idx:9]
    unsigned int key = ((unsigned int)y0 << 17) | ((unsigned int)x0 << 9) | (unsigned int)t;
    int pos = atomicAdd(&cnt[bin], 1);   // within-bin order nondeterminism is benign
    __syncthreads();

    // inclusive Hillis-Steele scan over the 256 padded bins
    if (t < NBINP) scan[t] = cnt[t];
    __syncthreads();
    for (int d = 1; d < NBINP; d <<= 1) {
        int v = 0;
        if (t < NBINP && t >= d) v = scan[t - d];
        __syncthreads();
        if (t < NBINP) scan[t] += v;
        __syncthreads();
    }
    if (t < NBINP) baseS[t] = scan[t] - cnt[t];   // exclusive base
    __syncthreads();

    keys[baseS[bin] + pos] = key;
    if (t <= B_) starts[t] = (t == B_) ? N_ : baseS[t * NYB];
}

__global__ __launch_bounds__(1024, 8) void roicut_kernel(
    const float* __restrict__ fm,
    const unsigned int* __restrict__ keys,
    const int* __restrict__ starts,
    float* __restrict__ out)
{
    int bid = blockIdx.x;
    int c = bid & 255;       // channel
    int a = bid >> 8;        // sample
    int t = threadIdx.x;     // 1024 threads

    int b0  = starts[a], b1 = starts[a + 1];
    int sub = t >> 8;        // 0..3: 4 boxes in flight (4 waves each)
    int q   = t & 255;       // pixel-quad within box tile
    int y   = q >> 3;        // 0..31
    int xg  = (q & 7) << 2;  // 0,4,...,28

    const float* plane = fm + (size_t)(a * C_ + c) * PLANE;

    for (int b = b0 + sub; b < b1; b += 4) {
        unsigned int v = keys[b];            // wave-uniform -> scalar load
        int y0 = (v >> 17) & 255;
        int x0 = (v >> 9) & 255;
        int i  = (int)(v & 511u);
        const float* p = plane + (y0 + y) * W_ + (x0 + xg);
        v4f vv;
        vv[0] = p[0];
        vv[1] = p[1];
        vv[2] = p[2];
        vv[3] = p[3];
        v4f* dst = (v4f*)(out + (((size_t)i << 18) + ((size_t)c << 10) + (size_t)(q << 2)));
        __builtin_nontemporal_store(vv, dst);
    }
}

extern "C" void kernel_launch(void* const* d_in, const int* in_sizes, int n_in,
                              void* d_out, int out_size, void* d_ws, size_t ws_size,
                              hipStream_t stream) {
    const float* fm    = (const float*)d_in[0];
    const int*   boxes = (const int*)d_in[1];
    const int*   assoc = (const int*)d_in[2];
    float*       out   = (float*)d_out;

    unsigned int* keys   = (unsigned int*)d_ws;    // 512 u32
    int*          starts = (int*)d_ws + N_;        // 9 ints

    group_boxes_kernel<<<1, N_, 0, stream>>>(boxes, assoc, keys, starts);

    int grid = B_ * C_;   // 2048 blocks: one per (sample, channel) plane
    roicut_kernel<<<grid, 1024, 0, stream>>>(fm, keys, starts, out);
}

// Round 9
// 168.937 us; speedup vs baseline: 1.1777x; 1.1777x over previous
//
#include <hip/hip_runtime.h>

// RoiCut: out[i, c, y, x] = fm[assoc[i], c, y0_i + y, x0_i + x]
// fm: [8, 256, 200, 200] fp32, boxes_yx: [512, 2] int32 (y0, x0), assoc: [512] int32
// out: [512, 256, 32, 32] fp32
//
// R8 strategy: R4 structure + XOR-rotated LDS reads to kill the 8-way bank conflict.
//  - R4's box loop: each ds_read_b32 had all 64 lanes on a stride-4 lattice of
//    8 banks (row stride 200 = 8 mod 32, quads 4-aligned) -> 8-way conflict
//    (2.94x, ~58 us/CU of LDS pipe, co-critical with the HBM store stream).
//  - Fix: instruction m reads element (m ^ (row&3)) of the quad -> each
//    instruction's lanes cover all 4 banks mod 4, keyed to row mod 4 which also
//    keys the 8*row bank offset -> 32 banks x 2 lanes = 2-way = free (m136).
//    Registers land XOR-rotated; un-rotate with 2 conditional static shuffles
//    (8 v_cndmask, constant indices only) before the nt dwordx4 store.
//  - staging stays canonical b128 conflict-free; reads exact-once coalesced;
//    half-plane blocks (80,000 B LDS, 2 blocks/CU); counting-scatter grouping.

typedef float v4f __attribute__((ext_vector_type(4)));

constexpr int C_     = 256;
constexpr int H_     = 200;
constexpr int W_     = 200;
constexpr int BOX_   = 32;
constexpr int N_     = 512;
constexpr int B_     = 8;
constexpr int PLANE  = H_ * W_;       // 40000 floats
constexpr int HROWS  = 100;           // rows per half
constexpr int HLDS   = HROWS * W_;    // 20000 floats = 80,000 B
constexpr int HLDS4  = HLDS / 4;      // 5000 float4

__global__ __launch_bounds__(512) void group_boxes_kernel(
    const int* __restrict__ boxes,
    const int* __restrict__ assoc,
    unsigned int* __restrict__ keys,
    int* __restrict__ starts)
{
    __shared__ int cnt[B_];
    __shared__ int base[B_ + 1];
    int t = threadIdx.x;   // 512 threads, one per box

    if (t < B_) cnt[t] = 0;
    __syncthreads();

    int y0 = boxes[2 * t];
    int x0 = boxes[2 * t + 1];
    y0 = min(max(y0, 0), H_ - BOX_);
    x0 = min(max(x0, 0), W_ - BOX_);
    int a = assoc[t];
    int pos = atomicAdd(&cnt[a], 1);   // order nondeterminism benign (disjoint outputs)
    __syncthreads();

    if (t == 0) {
        int s = 0;
        for (int i = 0; i < B_; ++i) { base[i] = s; s += cnt[i]; }
        base[B_] = s;
    }
    __syncthreads();

    // key: [y0:8 | x0:8 | idx:9]
    keys[base[a] + pos] = ((unsigned int)y0 << 17) | ((unsigned int)x0 << 9) | (unsigned int)t;
    if (t <= B_) starts[t] = base[t];
}

__global__ __launch_bounds__(1024, 8) void roicut_kernel(
    const float* __restrict__ fm,
    const unsigned int* __restrict__ keys,
    const int* __restrict__ starts,
    float* __restrict__ out)
{
    extern __shared__ float lds[];   // 80,000 B = half plane (100 rows x 200)

    int bid = blockIdx.x;
    int h = bid & 1;                 // half: rows [100h, 100h+100)
    int c = (bid >> 1) & 255;        // channel
    int a = bid >> 9;                // sample
    int t = threadIdx.x;             // 1024 threads

    // ---- stage half plane into LDS (canonical conflict-free b128 pattern) ----
    const v4f* src = (const v4f*)(fm + (size_t)(a * C_ + c) * PLANE) + h * HLDS4;
    v4f* l4 = (v4f*)lds;
    v4f r0 = src[t];
    v4f r1 = src[t + 1024];
    v4f r2 = src[t + 2048];
    v4f r3 = src[t + 3072];
    bool tail = t < (HLDS4 - 4096);   // t < 904
    v4f r4;
    if (tail) r4 = src[t + 4096];
    l4[t]        = r0;
    l4[t + 1024] = r1;
    l4[t + 2048] = r2;
    l4[t + 3072] = r3;
    if (tail) l4[t + 4096] = r4;
    __syncthreads();

    // ---- box loop: 4 boxes in flight (sub = 4 waves each) ----
    int b0 = starts[a], b1 = starts[a + 1];
    int sub = t >> 8;             // 0..3
    int q   = t & 255;            // pixel-quad within box tile
    int y   = q >> 3;             // 0..31
    int xg  = (q & 7) << 2;       // 0,4,...,28
    int rot = y & 3;              // per-row XOR rotation for bank spreading
    int hbase = h * HROWS;        // first plane row owned by this half

    for (int b = b0; b < b1; b += 4) {
        int bb = b + sub;
        if (bb < b1) {
            unsigned int v = keys[bb];
            int y0 = (v >> 17) & 255;
            int x0 = (v >> 9) & 255;
            int i  = (int)(v & 511u);
            int ly = y0 + y - hbase;          // row within this half
            if (ly >= 0 && ly < HROWS) {      // predicated rows (straddling boxes)
                const float* p = lds + ly * W_ + (x0 + xg);
                // XOR-rotated reads: instruction m touches element (m ^ rot);
                // per instruction, lanes cover 32 banks at 2-way -> conflict-free.
                v4f vv;
                vv[0] = p[0 ^ rot];
                vv[1] = p[1 ^ rot];
                vv[2] = p[2 ^ rot];
                vv[3] = p[3 ^ rot];
                // un-rotate: out[d] = vv[d ^ rot], via two conditional swaps
                v4f s1 = { vv[1], vv[0], vv[3], vv[2] };   // xor-by-1 shuffle
                vv = (rot & 1) ? s1 : vv;
                v4f s2 = { vv[2], vv[3], vv[0], vv[1] };   // xor-by-2 shuffle
                vv = (rot & 2) ? s2 : vv;
                v4f* dst = (v4f*)(out + (((size_t)i << 18) + ((size_t)c << 10) + (size_t)(q << 2)));
                __builtin_nontemporal_store(vv, dst);
            }
        }
    }
}

extern "C" void kernel_launch(void* const* d_in, const int* in_sizes, int n_in,
                              void* d_out, int out_size, void* d_ws, size_t ws_size,
                              hipStream_t stream) {
    const float* fm    = (const float*)d_in[0];
    const int*   boxes = (const int*)d_in[1];
    const int*   assoc = (const int*)d_in[2];
    float*       out   = (float*)d_out;

    unsigned int* keys   = (unsigned int*)d_ws;        // 512 u32
    int*          starts = (int*)d_ws + N_;            // 9 ints

    // allow 80,000 B dynamic LDS (host-side attribute; idempotent, no stream op)
    (void)hipFuncSetAttribute((const void*)roicut_kernel,
                              hipFuncAttributeMaxDynamicSharedMemorySize,
                              HLDS * (int)sizeof(float));

    group_boxes_kernel<<<1, N_, 0, stream>>>(boxes, assoc, keys, starts);

    int grid = B_ * C_ * 2;   // 4096 blocks: one per (sample, channel, half)
    roicut_kernel<<<grid, 1024, HLDS * sizeof(float), stream>>>(fm, keys, starts, out);
}